// Round 7
// baseline (85.159 us; speedup 1.0000x reference)
//
#include <hip/hip_runtime.h>

#define S_COEF 0.025f
#define EPS_C  1e-6f
#define L2E    1.4426950408889634f   // log2(e)

typedef float f32x4 __attribute__((ext_vector_type(4)));

__device__ __forceinline__ float fexp2(float v) { return __builtin_amdgcn_exp2f(v); }
__device__ __forceinline__ float flog2(float v) { return __builtin_amdgcn_logf(v); }

// DPP-assisted add: v += dpp(v). old=0 so out-of-pattern lanes add 0.
template<int CTRL, int RM, bool BC>
__device__ __forceinline__ float dpp_add(float v) {
    int t = __builtin_amdgcn_update_dpp(0, __builtin_bit_cast(int, v),
                                        CTRL, RM, 0xF, BC);
    return v + __builtin_bit_cast(float, t);
}

// Wave64 inclusive prefix sum: 6 VALU ops, no DS.
__device__ __forceinline__ float wave_incl_scan(float v) {
    v = dpp_add<0x111, 0xF, true >(v);  // row_shr:1
    v = dpp_add<0x112, 0xF, true >(v);  // row_shr:2
    v = dpp_add<0x114, 0xF, true >(v);  // row_shr:4
    v = dpp_add<0x118, 0xF, true >(v);  // row_shr:8
    v = dpp_add<0x142, 0xA, false>(v);  // row_bcast:15
    v = dpp_add<0x143, 0xC, false>(v);  // row_bcast:31
    return v;
}

// Streaming store with maximal cache-bypass: nt (L2 no-alloc) + sc0/sc1
// (system scope) -- goal: keep the 256 MB output stream from evicting x
// out of the 256 MiB Infinity Cache (plain nt alone leaves FETCH = x/2).
__device__ __forceinline__ void stream_store(float* dst, f32x4 v) {
    asm volatile("global_store_dwordx4 %0, %1, off sc0 sc1 nt"
                 :: "v"(dst), "v"(v) : "memory");
}

struct PcenParams { float alpha, delta, r, dr, uinv4, winv, ul4; };

__device__ __forceinline__ void pcen_group(
    const f32x4 cur, float& carry, const PcenParams& P,
    float* __restrict__ dst, bool store_ok)
{
    const float u = 1.0f - S_COEF;

    const float xl0 = cur.x * L2E, xl1 = cur.y * L2E;
    const float xl2 = cur.z * L2E, xl3 = cur.w * L2E;

    const float se0 = S_COEF * fexp2(xl0);
    const float se1 = S_COEF * fexp2(xl1);
    const float se2 = S_COEF * fexp2(xl2);
    const float se3 = S_COEF * fexp2(xl3);

    float b = se0;
    b = fmaf(u, b, se1);
    b = fmaf(u, b, se2);
    b = fmaf(u, b, se3);

    const float scaled = b * P.winv;
    const float ps     = wave_incl_scan(scaled);
    const float excl   = ps - scaled;

    const float m_in = P.ul4 * fmaf(excl, P.uinv4, carry);

    const float m0 = fmaf(u, m_in, se0);
    const float m1 = fmaf(u, m0,   se1);
    const float m2 = fmaf(u, m1,   se2);
    const float m3 = fmaf(u, m2,   se3);

    carry = __builtin_bit_cast(float,
                __builtin_amdgcn_readlane(__builtin_bit_cast(int, m3), 63));

    const float ed0 = fexp2(fmaf(-P.alpha, flog2(m0 + EPS_C), xl0));
    const float ed1 = fexp2(fmaf(-P.alpha, flog2(m1 + EPS_C), xl1));
    const float ed2 = fexp2(fmaf(-P.alpha, flog2(m2 + EPS_C), xl2));
    const float ed3 = fexp2(fmaf(-P.alpha, flog2(m3 + EPS_C), xl3));

    const float o0 = fexp2(P.r * flog2(ed0 + P.delta)) - P.dr;
    const float o1 = fexp2(P.r * flog2(ed1 + P.delta)) - P.dr;
    const float o2 = fexp2(P.r * flog2(ed2 + P.delta)) - P.dr;
    const float o3 = fexp2(P.r * flog2(ed3 + P.delta)) - P.dr;

    if (store_ok) {
        f32x4 o4 = {o0, o1, o2, o3};
        stream_store(dst, o4);
    }
}

__global__ __launch_bounds__(256) void pcen_kernel(
    const float* __restrict__ x,
    const float* __restrict__ p_la,
    const float* __restrict__ p_ld,
    const float* __restrict__ p_lr,
    float* __restrict__ out,
    int rows, int T)
{
    const int lane = threadIdx.x & 63;
    const int wid  = blockIdx.x * (blockDim.x >> 6) + (threadIdx.x >> 6);
    if (wid >= rows) return;

    PcenParams P;
    P.alpha = fminf(fmaxf(__expf(p_la[0]), 0.01f), 1.0f);
    P.delta = fminf(fmaxf(__expf(p_ld[0]), 0.01f), 5.0f);
    P.r     = fminf(fmaxf(__expf(p_lr[0]), 0.01f), 1.0f);
    P.dr    = fexp2(P.r * flog2(P.delta));

    const float u     = 1.0f - S_COEF;
    const float log2u = flog2(u);
    P.uinv4 = fexp2(-4.0f * log2u);
    P.winv  = fexp2(-4.0f * (float)lane * log2u);
    P.ul4   = fexp2( 4.0f * (float)lane * log2u);

    const float* __restrict__ xr  = x   + (size_t)wid * T;
    float* __restrict__       orr = out + (size_t)wid * T;

    const int nfull = T >> 8;                // 31 full groups (T=8000)
    const int myoff = lane * 4;
    float carry = 0.0f;

    // prefetch depth 2 (T >= 512 for full groups >= 2)
    f32x4 cur = *(const f32x4*)(xr + myoff);
    f32x4 n1  = *(const f32x4*)(xr + 256 + myoff);

    for (int g = 0; g < nfull; ++g) {
        const int pidx = ((g + 2) << 8) + myoff;
        f32x4 n2 = (pidx < T) ? *(const f32x4*)(xr + pidx)
                              : (f32x4){0.f, 0.f, 0.f, 0.f};

        pcen_group(cur, carry, P, orr + (g << 8) + myoff, true);

        cur = n1;
        n1  = n2;
    }

    // tail group: t in [nfull*256, T); valid lanes only
    const int tbase = nfull << 8;
    if (tbase < T)
        pcen_group(cur, carry, P, orr + tbase + myoff, tbase + myoff < T);
}

extern "C" void kernel_launch(void* const* d_in, const int* in_sizes, int n_in,
                              void* d_out, int out_size, void* d_ws, size_t ws_size,
                              hipStream_t stream) {
    const float* x  = (const float*)d_in[0];
    const float* la = (const float*)d_in[1];
    const float* ld = (const float*)d_in[2];
    const float* lr = (const float*)d_in[3];
    float* out = (float*)d_out;

    const int T    = 8000;
    const int rows = in_sizes[0] / T;        // 64*128 = 8192
    const int wavesPerBlock = 4;             // blockDim 256
    const int blocks = (rows + wavesPerBlock - 1) / wavesPerBlock;

    hipLaunchKernelGGL(pcen_kernel, dim3(blocks), dim3(256), 0, stream,
                       x, la, ld, lr, out, rows, T);
}